// Round 2
// baseline (644.160 us; speedup 1.0000x reference)
//
#include <hip/hip_runtime.h>

typedef __attribute__((ext_vector_type(8))) short short8;
typedef __attribute__((ext_vector_type(4))) float f32x4;

#define FF 256   // hidden features
#define NHEAD 4
#define HDIM 64

__device__ __forceinline__ unsigned short f2bf(float f) {
  union { unsigned u; float f; } v; v.f = f;
  unsigned r = v.u + 0x7FFFu + ((v.u >> 16) & 1u);
  return (unsigned short)(r >> 16);
}

// ---------------- fp32 -> bf16 conversion ----------------
__global__ __launch_bounds__(256) void cvt_bf16_kernel(const float* __restrict__ in,
                                                       unsigned short* __restrict__ out,
                                                       int n4) {
  int i = blockIdx.x * blockDim.x + threadIdx.x;
  if (i < n4) {
    f32x4 v = ((const f32x4*)in)[i];
    ushort4 o;
    o.x = f2bf(v.x); o.y = f2bf(v.y); o.z = f2bf(v.z); o.w = f2bf(v.w);
    ((ushort4*)out)[i] = o;
  }
}

// ---------------- CSR build ----------------
__global__ void hist_kernel(const int* __restrict__ dst, int* __restrict__ deg,
                            int E, int N) {
  int i = blockIdx.x * blockDim.x + threadIdx.x;
  if (i < E) {
    int d = dst[i];
    if ((unsigned)d < (unsigned)N) atomicAdd(&deg[d], 1);
  }
}

__global__ __launch_bounds__(256) void scan_chunks(const int* __restrict__ deg,
                                                   int* __restrict__ excl,
                                                   int* __restrict__ csum, int N) {
  __shared__ int s[256];
  int t = threadIdx.x;
  int base = blockIdx.x * 1024 + t * 4;
  int v[4];
  int sum = 0;
#pragma unroll
  for (int i = 0; i < 4; ++i) {
    v[i] = (base + i < N) ? deg[base + i] : 0;
    sum += v[i];
  }
  s[t] = sum;
  __syncthreads();
  for (int off = 1; off < 256; off <<= 1) {
    int x = (t >= off) ? s[t - off] : 0;
    __syncthreads();
    s[t] += x;
    __syncthreads();
  }
  int run = s[t] - sum;
#pragma unroll
  for (int i = 0; i < 4; ++i) {
    if (base + i < N) excl[base + i] = run;
    run += v[i];
  }
  if (t == 255) csum[blockIdx.x] = s[255];
}

__global__ void scan_sums(int* __restrict__ csum, int nchunks) {
  if (threadIdx.x == 0 && blockIdx.x == 0) {
    int run = 0;
    for (int i = 0; i < nchunks; ++i) {
      int c = csum[i];
      csum[i] = run;
      run += c;
    }
  }
}

__global__ void finalize_rows(const int* __restrict__ excl, const int* __restrict__ csum,
                              int* __restrict__ row_start, int* __restrict__ cursor,
                              int N, int E) {
  int i = blockIdx.x * blockDim.x + threadIdx.x;
  if (i < N) {
    int v = excl[i] + csum[i >> 10];
    row_start[i] = v;
    cursor[i] = v;
  }
  if (i == 0) row_start[N] = E;
}

__global__ void scatter_kernel(const int* __restrict__ src, const int* __restrict__ dst,
                               int* __restrict__ cursor, int* __restrict__ sorted_src,
                               int E, int N) {
  int i = blockIdx.x * blockDim.x + threadIdx.x;
  if (i < E) {
    int d = dst[i];
    int s = src[i];
    if ((unsigned)d < (unsigned)N) {
      int p = atomicAdd(&cursor[d], 1);
      if ((unsigned)p < (unsigned)E)
        sorted_src[p] = ((unsigned)s < (unsigned)N) ? s : 0;
    }
  }
}

// ---------------- GEMM: C[M x (COLGROUPS*64)] = A(bf16,[M x 256]) * B(bf16,[ncols x 256])^T
// One wave computes 16 rows x 64 cols via 4 MFMA accumulators; 4 waves/block
// share a row-tile, covering colGroups (COLGROUPS=4) or 4 row-tiles (COLGROUPS=1).
template <int COLGROUPS>
__global__ __launch_bounds__(256) void gemm_bt(const unsigned short* __restrict__ A,
                                               const unsigned short* __restrict__ B,
                                               float* __restrict__ C,
                                               const float* __restrict__ bias,
                                               int M) {
  const int K = 256;
  const int NCOL = COLGROUPS * 64;
  int wave = threadIdx.x >> 6;
  int lane = threadIdx.x & 63;
  int gw = blockIdx.x * 4 + wave;
  int rowTile = gw / COLGROUPS;
  int colGroup = gw % COLGROUPS;
  int row0 = rowTile * 16;
  if (row0 >= M) return;
  int col0 = colGroup * 64;
  int lr = lane & 15;
  int quad = lane >> 4;

  int arow = row0 + lr;
  if (arow >= M) arow = M - 1;
  const unsigned short* Ap = A + (size_t)arow * K + quad * 8;

  f32x4 acc[4] = {f32x4{0, 0, 0, 0}, f32x4{0, 0, 0, 0}, f32x4{0, 0, 0, 0},
                  f32x4{0, 0, 0, 0}};
#pragma unroll
  for (int kk = 0; kk < 8; ++kk) {
    short8 a = *(const short8*)(Ap + kk * 32);
#pragma unroll
    for (int t = 0; t < 4; ++t) {
      const unsigned short* Bp = B + (size_t)(col0 + 16 * t + lr) * K + quad * 8 + kk * 32;
      short8 b = *(const short8*)Bp;
      acc[t] = __builtin_amdgcn_mfma_f32_16x16x32_bf16(a, b, acc[t], 0, 0, 0);
    }
  }
#pragma unroll
  for (int t = 0; t < 4; ++t) {
#pragma unroll
    for (int r = 0; r < 4; ++r) {
      int row = row0 + quad * 4 + r;
      if (row < M) {
        int col = col0 + 16 * t + lr;
        float v = acc[t][r];
        if (bias) v += bias[col];
        C[(size_t)row * NCOL + col] = v;
      }
    }
  }
}

// ---------------- attention scores ----------------
__global__ __launch_bounds__(256) void scores_kernel(const float* __restrict__ h,
                                                     const float* __restrict__ a_src,
                                                     const float* __restrict__ a_dst,
                                                     float* __restrict__ sS,
                                                     float* __restrict__ sD, int N) {
  __shared__ float As[FF], Ad[FF];
  int t = threadIdx.x;
  As[t] = a_src[t];
  Ad[t] = a_dst[t];
  __syncthreads();
  int g = blockIdx.x * 256 + t;
  if (g >= N * NHEAD) return;
  int n = g >> 2;
  int hh = g & 3;
  const f32x4* hp = (const f32x4*)(h + (size_t)n * FF + hh * HDIM);
  const float* ap = As + hh * HDIM;
  const float* dp = Ad + hh * HDIM;
  float ss = 0.f, sd = 0.f;
#pragma unroll
  for (int i = 0; i < 16; ++i) {
    f32x4 v = hp[i];
    ss += v.x * ap[i * 4 + 0] + v.y * ap[i * 4 + 1] + v.z * ap[i * 4 + 2] + v.w * ap[i * 4 + 3];
    sd += v.x * dp[i * 4 + 0] + v.y * dp[i * 4 + 1] + v.z * dp[i * 4 + 2] + v.w * dp[i * 4 + 3];
  }
  sS[g] = ss;
  sD[g] = sd;
}

// ---------------- aggregation: online softmax over in-edges + BN + ELU ----------------
// Writes bf16 (feeds next GEMM). Optionally nothing to fp32 here; head handles final.
__global__ __launch_bounds__(256) void aggregate_kernel(
    const float* __restrict__ hprev, const float* __restrict__ sS,
    const float* __restrict__ sD, const int* __restrict__ row_start,
    const int* __restrict__ sorted_src, const float* __restrict__ gamma,
    const float* __restrict__ beta, const float* __restrict__ mean,
    const float* __restrict__ var, unsigned short* __restrict__ hout, int N) {
  int n = blockIdx.x;
  int tid = threadIdx.x;           // f = h*64 + d
  int hh = tid >> 6;
  float sdv = sD[n * NHEAD + hh];
  int jb = row_start[n];
  int je = row_start[n + 1];
  float m = 0.f, l = 0.f, o = 0.f;  // running max clamped at 0 (reference semantics)
  for (int j = jb; j < je; ++j) {
    int s = sorted_src[j];
    float e = sS[s * NHEAD + hh] + sdv;
    e = (e >= 0.f) ? e : 0.2f * e;
    float hv = hprev[(size_t)s * FF + tid];
    if (e <= m) {
      float w = __expf(e - m);
      l += w;
      o += w * hv;
    } else {
      float sc = __expf(m - e);
      l = l * sc + 1.f;
      o = o * sc + hv;
      m = e;
    }
  }
  float val = o / fmaxf(l, 1e-9f);
  float g = gamma[tid], b = beta[tid], mu = mean[tid], vr = var[tid];
  val = (val - mu) * rsqrtf(vr + 1e-5f) * g + b;
  val = (val > 0.f) ? val : expm1f(val);
  hout[(size_t)n * FF + tid] = f2bf(val);
}

// ---------------- launch ----------------
extern "C" void kernel_launch(void* const* d_in, const int* in_sizes, int n_in,
                              void* d_out, int out_size, void* d_ws, size_t ws_size,
                              hipStream_t stream) {
  const float* x   = (const float*)d_in[0];
  const int* ei    = (const int*)d_in[1];
  const float* W1  = (const float*)d_in[2];
  const float* as1 = (const float*)d_in[3];
  const float* ad1 = (const float*)d_in[4];
  const float* g1  = (const float*)d_in[5];
  const float* b1  = (const float*)d_in[6];
  const float* m1  = (const float*)d_in[7];
  const float* v1  = (const float*)d_in[8];
  const float* W2  = (const float*)d_in[9];
  const float* as2 = (const float*)d_in[10];
  const float* ad2 = (const float*)d_in[11];
  const float* g2  = (const float*)d_in[12];
  const float* b2  = (const float*)d_in[13];
  const float* m2  = (const float*)d_in[14];
  const float* v2  = (const float*)d_in[15];
  const float* Wc  = (const float*)d_in[16];
  const float* bc  = (const float*)d_in[17];

  const int N = in_sizes[0] / FF;
  const int E = in_sizes[1] / 2;
  const int* srcIdx = ei;
  const int* dstIdx = ei + E;

  char* ws = (char*)d_ws;
  size_t off = 0;
  auto take = [&](size_t bytes) -> void* {
    void* p = ws + off;
    off += (bytes + 255) & ~(size_t)255;
    return p;
  };
  int* deg        = (int*)take((size_t)N * 4);
  int* excl       = (int*)take((size_t)N * 4);
  int* csum       = (int*)take(256 * 4);
  int* row_start  = (int*)take(((size_t)N + 1) * 4);
  int* cursor     = (int*)take((size_t)N * 4);
  int* sorted_src = (int*)take((size_t)E * 4);
  float* hbuf     = (float*)take((size_t)N * FF * 4);
  float* sS       = (float*)take((size_t)N * NHEAD * 4);
  float* sD       = (float*)take((size_t)N * NHEAD * 4);
  unsigned short* hb  = (unsigned short*)take((size_t)N * FF * 2);  // bf16 layer output
  unsigned short* xb  = (unsigned short*)take((size_t)N * FF * 2);  // bf16 x
  unsigned short* w1b = (unsigned short*)take((size_t)FF * FF * 2);
  unsigned short* w2b = (unsigned short*)take((size_t)FF * FF * 2);
  unsigned short* wcb = (unsigned short*)take((size_t)64 * FF * 2);

  const int tpb = 256;

  // dtype conversions (fp32 inputs -> bf16 MFMA operands)
  {
    int n4 = (N * FF) / 4;
    cvt_bf16_kernel<<<(n4 + tpb - 1) / tpb, tpb, 0, stream>>>(x, xb, n4);
    int w4 = (FF * FF) / 4;
    cvt_bf16_kernel<<<(w4 + tpb - 1) / tpb, tpb, 0, stream>>>(W1, w1b, w4);
    cvt_bf16_kernel<<<(w4 + tpb - 1) / tpb, tpb, 0, stream>>>(W2, w2b, w4);
    int wc4 = (64 * FF) / 4;
    cvt_bf16_kernel<<<(wc4 + tpb - 1) / tpb, tpb, 0, stream>>>(Wc, wcb, wc4);
  }

  // CSR build (dst-sorted edge list), reused by both layers
  hipMemsetAsync(deg, 0, (size_t)N * 4, stream);
  hist_kernel<<<(E + tpb - 1) / tpb, tpb, 0, stream>>>(dstIdx, deg, E, N);
  int nchunks = (N + 1023) / 1024;
  scan_chunks<<<nchunks, 256, 0, stream>>>(deg, excl, csum, N);
  scan_sums<<<1, 64, 0, stream>>>(csum, nchunks);
  finalize_rows<<<(N + tpb - 1) / tpb, tpb, 0, stream>>>(excl, csum, row_start, cursor, N, E);
  scatter_kernel<<<(E + tpb - 1) / tpb, tpb, 0, stream>>>(srcIdx, dstIdx, cursor, sorted_src, E, N);

  int rowTiles = (N + 15) / 16;

  // layer 1
  gemm_bt<4><<<rowTiles, 256, 0, stream>>>(xb, w1b, hbuf, (const float*)nullptr, N);
  scores_kernel<<<(N * NHEAD + tpb - 1) / tpb, tpb, 0, stream>>>(hbuf, as1, ad1, sS, sD, N);
  aggregate_kernel<<<N, 256, 0, stream>>>(hbuf, sS, sD, row_start, sorted_src, g1, b1, m1, v1,
                                          hb, N);
  // layer 2
  gemm_bt<4><<<rowTiles, 256, 0, stream>>>(hb, w2b, hbuf, (const float*)nullptr, N);
  scores_kernel<<<(N * NHEAD + tpb - 1) / tpb, tpb, 0, stream>>>(hbuf, as2, ad2, sS, sD, N);
  aggregate_kernel<<<N, 256, 0, stream>>>(hbuf, sS, sD, row_start, sorted_src, g2, b2, m2, v2,
                                          hb, N);
  // classifier head -> fp32 out (+bias)
  gemm_bt<1><<<(rowTiles + 3) / 4, 256, 0, stream>>>(hb, wcb, (float*)d_out, bc, N);
}

// Round 3
// 534.848 us; speedup vs baseline: 1.2044x; 1.2044x over previous
//
#include <hip/hip_runtime.h>

typedef __attribute__((ext_vector_type(8))) short short8;
typedef __attribute__((ext_vector_type(4))) float f32x4;

#define FF 256   // hidden features
#define NHEAD 4
#define HDIM 64

__device__ __forceinline__ float bf2f(unsigned short u) {
  union { unsigned u; float f; } v; v.u = ((unsigned)u) << 16; return v.f;
}
__device__ __forceinline__ unsigned short f2bf(float f) {
  union { unsigned u; float f; } v; v.f = f;
  unsigned r = v.u + 0x7FFFu + ((v.u >> 16) & 1u);
  return (unsigned short)(r >> 16);
}

// ---------------- fp32 -> bf16 conversion ----------------
__global__ __launch_bounds__(256) void cvt_bf16_kernel(const float* __restrict__ in,
                                                       unsigned short* __restrict__ out,
                                                       int n4) {
  int i = blockIdx.x * blockDim.x + threadIdx.x;
  if (i < n4) {
    f32x4 v = ((const f32x4*)in)[i];
    ushort4 o;
    o.x = f2bf(v.x); o.y = f2bf(v.y); o.z = f2bf(v.z); o.w = f2bf(v.w);
    ((ushort4*)out)[i] = o;
  }
}

// ---------------- CSR build ----------------
__global__ void hist_kernel(const int* __restrict__ dst, int* __restrict__ deg,
                            int E, int N) {
  int i = blockIdx.x * blockDim.x + threadIdx.x;
  if (i < E) {
    int d = dst[i];
    if ((unsigned)d < (unsigned)N) atomicAdd(&deg[d], 1);
  }
}

__global__ __launch_bounds__(256) void scan_chunks(const int* __restrict__ deg,
                                                   int* __restrict__ excl,
                                                   int* __restrict__ csum, int N) {
  __shared__ int s[256];
  int t = threadIdx.x;
  int base = blockIdx.x * 1024 + t * 4;
  int v[4];
  int sum = 0;
#pragma unroll
  for (int i = 0; i < 4; ++i) {
    v[i] = (base + i < N) ? deg[base + i] : 0;
    sum += v[i];
  }
  s[t] = sum;
  __syncthreads();
  for (int off = 1; off < 256; off <<= 1) {
    int x = (t >= off) ? s[t - off] : 0;
    __syncthreads();
    s[t] += x;
    __syncthreads();
  }
  int run = s[t] - sum;
#pragma unroll
  for (int i = 0; i < 4; ++i) {
    if (base + i < N) excl[base + i] = run;
    run += v[i];
  }
  if (t == 255) csum[blockIdx.x] = s[255];
}

__global__ void scan_sums(int* __restrict__ csum, int nchunks) {
  if (threadIdx.x == 0 && blockIdx.x == 0) {
    int run = 0;
    for (int i = 0; i < nchunks; ++i) {
      int c = csum[i];
      csum[i] = run;
      run += c;
    }
  }
}

__global__ void finalize_rows(const int* __restrict__ excl, const int* __restrict__ csum,
                              int* __restrict__ row_start, int* __restrict__ cursor,
                              int N, int E) {
  int i = blockIdx.x * blockDim.x + threadIdx.x;
  if (i < N) {
    int v = excl[i] + csum[i >> 10];
    row_start[i] = v;
    cursor[i] = v;
  }
  if (i == 0) row_start[N] = E;
}

__global__ void scatter_kernel(const int* __restrict__ src, const int* __restrict__ dst,
                               int* __restrict__ cursor, int* __restrict__ sorted_src,
                               int E, int N) {
  int i = blockIdx.x * blockDim.x + threadIdx.x;
  if (i < E) {
    int d = dst[i];
    int s = src[i];
    if ((unsigned)d < (unsigned)N) {
      int p = atomicAdd(&cursor[d], 1);
      if ((unsigned)p < (unsigned)E)
        sorted_src[p] = ((unsigned)s < (unsigned)N) ? s : 0;
    }
  }
}

// ---------------- GEMM: C = A(bf16,[M x 256]) * B(bf16,[ncols x 256])^T ----------------
// BF16OUT: write ushort (feeds scores/aggregate/next gemm); else fp32 (+bias) for head.
template <int COLGROUPS, bool BF16OUT>
__global__ __launch_bounds__(256) void gemm_bt(const unsigned short* __restrict__ A,
                                               const unsigned short* __restrict__ B,
                                               float* __restrict__ Cf,
                                               unsigned short* __restrict__ Cb,
                                               const float* __restrict__ bias,
                                               int M) {
  const int K = 256;
  const int NCOL = COLGROUPS * 64;
  int wave = threadIdx.x >> 6;
  int lane = threadIdx.x & 63;
  int gw = blockIdx.x * 4 + wave;
  int rowTile = gw / COLGROUPS;
  int colGroup = gw % COLGROUPS;
  int row0 = rowTile * 16;
  if (row0 >= M) return;
  int col0 = colGroup * 64;
  int lr = lane & 15;
  int quad = lane >> 4;

  int arow = row0 + lr;
  if (arow >= M) arow = M - 1;
  const unsigned short* Ap = A + (size_t)arow * K + quad * 8;

  f32x4 acc[4] = {f32x4{0, 0, 0, 0}, f32x4{0, 0, 0, 0}, f32x4{0, 0, 0, 0},
                  f32x4{0, 0, 0, 0}};
#pragma unroll
  for (int kk = 0; kk < 8; ++kk) {
    short8 a = *(const short8*)(Ap + kk * 32);
#pragma unroll
    for (int t = 0; t < 4; ++t) {
      const unsigned short* Bp = B + (size_t)(col0 + 16 * t + lr) * K + quad * 8 + kk * 32;
      short8 b = *(const short8*)Bp;
      acc[t] = __builtin_amdgcn_mfma_f32_16x16x32_bf16(a, b, acc[t], 0, 0, 0);
    }
  }
#pragma unroll
  for (int t = 0; t < 4; ++t) {
#pragma unroll
    for (int r = 0; r < 4; ++r) {
      int row = row0 + quad * 4 + r;
      if (row < M) {
        int col = col0 + 16 * t + lr;
        float v = acc[t][r];
        if (BF16OUT) {
          Cb[(size_t)row * NCOL + col] = f2bf(v);
        } else {
          if (bias) v += bias[col];
          Cf[(size_t)row * NCOL + col] = v;
        }
      }
    }
  }
}

// ---------------- attention scores (bf16 h) ----------------
__global__ __launch_bounds__(256) void scores_kernel(const unsigned short* __restrict__ h,
                                                     const float* __restrict__ a_src,
                                                     const float* __restrict__ a_dst,
                                                     float* __restrict__ sS,
                                                     float* __restrict__ sD, int N) {
  __shared__ float As[FF], Ad[FF];
  int t = threadIdx.x;
  As[t] = a_src[t];
  Ad[t] = a_dst[t];
  __syncthreads();
  int g = blockIdx.x * 256 + t;
  if (g >= N * NHEAD) return;
  int n = g >> 2;
  int hh = g & 3;
  const ushort4* hp = (const ushort4*)(h + (size_t)n * FF + hh * HDIM);
  const float* ap = As + hh * HDIM;
  const float* dp = Ad + hh * HDIM;
  float ss = 0.f, sd = 0.f;
#pragma unroll
  for (int i = 0; i < 16; ++i) {
    ushort4 u = hp[i];
    float v0 = bf2f(u.x), v1 = bf2f(u.y), v2 = bf2f(u.z), v3 = bf2f(u.w);
    ss += v0 * ap[i * 4 + 0] + v1 * ap[i * 4 + 1] + v2 * ap[i * 4 + 2] + v3 * ap[i * 4 + 3];
    sd += v0 * dp[i * 4 + 0] + v1 * dp[i * 4 + 1] + v2 * dp[i * 4 + 2] + v3 * dp[i * 4 + 3];
  }
  sS[g] = ss;
  sD[g] = sd;
}

// ---------------- phase 1: per-(node,head) softmax stats (m clamped at 0, 1/l) ----------
__global__ __launch_bounds__(256) void softmax_stats_kernel(
    const float* __restrict__ sS, const float* __restrict__ sD,
    const int* __restrict__ row_start, const int* __restrict__ sorted_src,
    float* __restrict__ mbuf, float* __restrict__ linv, int N) {
  int g = blockIdx.x * 256 + threadIdx.x;
  if (g >= N * NHEAD) return;
  int n = g >> 2;
  int hh = g & 3;
  float sdv = sD[g];
  int jb = row_start[n];
  int je = row_start[n + 1];
  float m = 0.f, l = 0.f;
  for (int j = jb; j < je; ++j) {
    int s = sorted_src[j];
    float e = sS[s * NHEAD + hh] + sdv;
    e = (e >= 0.f) ? e : 0.2f * e;
    if (e <= m) {
      l += __expf(e - m);
    } else {
      l = l * __expf(m - e) + 1.f;
      m = e;
    }
  }
  mbuf[g] = m;
  linv[g] = 1.f / fmaxf(l, 1e-9f);
}

// ---------------- phase 2: branch-free weighted gather + BN + ELU, bf16 out ----------
__global__ __launch_bounds__(256) void aggregate_kernel(
    const unsigned short* __restrict__ hprev, const float* __restrict__ sS,
    const float* __restrict__ sD, const float* __restrict__ mbuf,
    const float* __restrict__ linv, const int* __restrict__ row_start,
    const int* __restrict__ sorted_src, const float* __restrict__ gamma,
    const float* __restrict__ beta, const float* __restrict__ mean,
    const float* __restrict__ var, unsigned short* __restrict__ hout, int N) {
  int n = blockIdx.x;
  int tid = threadIdx.x;  // f = h*64 + d
  int hh = tid >> 6;
  float sdv = sD[n * NHEAD + hh];
  float m = mbuf[n * NHEAD + hh];
  float li = linv[n * NHEAD + hh];
  int jb = row_start[n];
  int je = row_start[n + 1];
  const unsigned short* hp = hprev + tid;
  float o = 0.f;
  int j = jb;
  for (; j + 3 < je; j += 4) {
    int s0 = sorted_src[j + 0];
    int s1 = sorted_src[j + 1];
    int s2 = sorted_src[j + 2];
    int s3 = sorted_src[j + 3];
    float e0 = sS[s0 * NHEAD + hh] + sdv;
    float e1 = sS[s1 * NHEAD + hh] + sdv;
    float e2 = sS[s2 * NHEAD + hh] + sdv;
    float e3 = sS[s3 * NHEAD + hh] + sdv;
    e0 = (e0 >= 0.f) ? e0 : 0.2f * e0;
    e1 = (e1 >= 0.f) ? e1 : 0.2f * e1;
    e2 = (e2 >= 0.f) ? e2 : 0.2f * e2;
    e3 = (e3 >= 0.f) ? e3 : 0.2f * e3;
    float w0 = __expf(e0 - m);
    float w1 = __expf(e1 - m);
    float w2 = __expf(e2 - m);
    float w3 = __expf(e3 - m);
    float h0 = bf2f(hp[(size_t)s0 * FF]);
    float h1 = bf2f(hp[(size_t)s1 * FF]);
    float h2 = bf2f(hp[(size_t)s2 * FF]);
    float h3 = bf2f(hp[(size_t)s3 * FF]);
    o += w0 * h0 + w1 * h1 + w2 * h2 + w3 * h3;
  }
  for (; j < je; ++j) {
    int s = sorted_src[j];
    float e = sS[s * NHEAD + hh] + sdv;
    e = (e >= 0.f) ? e : 0.2f * e;
    o += __expf(e - m) * bf2f(hp[(size_t)s * FF]);
  }
  float val = o * li;
  float g = gamma[tid], b = beta[tid], mu = mean[tid], vr = var[tid];
  val = (val - mu) * rsqrtf(vr + 1e-5f) * g + b;
  val = (val > 0.f) ? val : expm1f(val);
  hout[(size_t)n * FF + tid] = f2bf(val);
}

// ---------------- launch ----------------
extern "C" void kernel_launch(void* const* d_in, const int* in_sizes, int n_in,
                              void* d_out, int out_size, void* d_ws, size_t ws_size,
                              hipStream_t stream) {
  const float* x   = (const float*)d_in[0];
  const int* ei    = (const int*)d_in[1];
  const float* W1  = (const float*)d_in[2];
  const float* as1 = (const float*)d_in[3];
  const float* ad1 = (const float*)d_in[4];
  const float* g1  = (const float*)d_in[5];
  const float* b1  = (const float*)d_in[6];
  const float* m1  = (const float*)d_in[7];
  const float* v1  = (const float*)d_in[8];
  const float* W2  = (const float*)d_in[9];
  const float* as2 = (const float*)d_in[10];
  const float* ad2 = (const float*)d_in[11];
  const float* g2  = (const float*)d_in[12];
  const float* b2  = (const float*)d_in[13];
  const float* m2  = (const float*)d_in[14];
  const float* v2  = (const float*)d_in[15];
  const float* Wc  = (const float*)d_in[16];
  const float* bc  = (const float*)d_in[17];

  const int N = in_sizes[0] / FF;
  const int E = in_sizes[1] / 2;
  const int* srcIdx = ei;
  const int* dstIdx = ei + E;

  char* ws = (char*)d_ws;
  size_t off = 0;
  auto take = [&](size_t bytes) -> void* {
    void* p = ws + off;
    off += (bytes + 255) & ~(size_t)255;
    return p;
  };
  int* deg        = (int*)take((size_t)N * 4);
  int* excl       = (int*)take((size_t)N * 4);
  int* csum       = (int*)take(256 * 4);
  int* row_start  = (int*)take(((size_t)N + 1) * 4);
  int* cursor     = (int*)take((size_t)N * 4);
  int* sorted_src = (int*)take((size_t)E * 4);
  float* sS       = (float*)take((size_t)N * NHEAD * 4);
  float* sD       = (float*)take((size_t)N * NHEAD * 4);
  float* mbuf     = (float*)take((size_t)N * NHEAD * 4);
  float* linv     = (float*)take((size_t)N * NHEAD * 4);
  unsigned short* hpre = (unsigned short*)take((size_t)N * FF * 2);  // bf16 pre-agg h
  unsigned short* hact = (unsigned short*)take((size_t)N * FF * 2);  // bf16 post BN/ELU
  unsigned short* xb   = (unsigned short*)take((size_t)N * FF * 2);  // bf16 x
  unsigned short* w1b  = (unsigned short*)take((size_t)FF * FF * 2);
  unsigned short* w2b  = (unsigned short*)take((size_t)FF * FF * 2);
  unsigned short* wcb  = (unsigned short*)take((size_t)64 * FF * 2);

  const int tpb = 256;

  // dtype conversions
  {
    int n4 = (N * FF) / 4;
    cvt_bf16_kernel<<<(n4 + tpb - 1) / tpb, tpb, 0, stream>>>(x, xb, n4);
    int w4 = (FF * FF) / 4;
    cvt_bf16_kernel<<<(w4 + tpb - 1) / tpb, tpb, 0, stream>>>(W1, w1b, w4);
    cvt_bf16_kernel<<<(w4 + tpb - 1) / tpb, tpb, 0, stream>>>(W2, w2b, w4);
    int wc4 = (64 * FF) / 4;
    cvt_bf16_kernel<<<(wc4 + tpb - 1) / tpb, tpb, 0, stream>>>(Wc, wcb, wc4);
  }

  // CSR build (dst-sorted edge list), reused by both layers
  hipMemsetAsync(deg, 0, (size_t)N * 4, stream);
  hist_kernel<<<(E + tpb - 1) / tpb, tpb, 0, stream>>>(dstIdx, deg, E, N);
  int nchunks = (N + 1023) / 1024;
  scan_chunks<<<nchunks, 256, 0, stream>>>(deg, excl, csum, N);
  scan_sums<<<1, 64, 0, stream>>>(csum, nchunks);
  finalize_rows<<<(N + tpb - 1) / tpb, tpb, 0, stream>>>(excl, csum, row_start, cursor, N, E);
  scatter_kernel<<<(E + tpb - 1) / tpb, tpb, 0, stream>>>(srcIdx, dstIdx, cursor, sorted_src, E, N);

  int rowTiles = (N + 15) / 16;
  int nhBlocks = (N * NHEAD + tpb - 1) / tpb;

  // layer 1
  gemm_bt<4, true><<<rowTiles, 256, 0, stream>>>(xb, w1b, (float*)nullptr, hpre,
                                                 (const float*)nullptr, N);
  scores_kernel<<<nhBlocks, tpb, 0, stream>>>(hpre, as1, ad1, sS, sD, N);
  softmax_stats_kernel<<<nhBlocks, tpb, 0, stream>>>(sS, sD, row_start, sorted_src, mbuf, linv, N);
  aggregate_kernel<<<N, 256, 0, stream>>>(hpre, sS, sD, mbuf, linv, row_start, sorted_src,
                                          g1, b1, m1, v1, hact, N);
  // layer 2
  gemm_bt<4, true><<<rowTiles, 256, 0, stream>>>(hact, w2b, (float*)nullptr, hpre,
                                                 (const float*)nullptr, N);
  scores_kernel<<<nhBlocks, tpb, 0, stream>>>(hpre, as2, ad2, sS, sD, N);
  softmax_stats_kernel<<<nhBlocks, tpb, 0, stream>>>(sS, sD, row_start, sorted_src, mbuf, linv, N);
  aggregate_kernel<<<N, 256, 0, stream>>>(hpre, sS, sD, mbuf, linv, row_start, sorted_src,
                                          g2, b2, m2, v2, hact, N);
  // classifier head -> fp32 out (+bias)
  gemm_bt<1, false><<<(rowTiles + 3) / 4, 256, 0, stream>>>(hact, wcb, (float*)d_out,
                                                            (unsigned short*)nullptr, bc, N);
}

// Round 4
// 478.857 us; speedup vs baseline: 1.3452x; 1.1169x over previous
//
#include <hip/hip_runtime.h>

typedef __attribute__((ext_vector_type(8))) short short8;
typedef __attribute__((ext_vector_type(4))) float f32x4;

#define FF 256   // hidden features
#define NHEAD 4
#define HDIM 64

__device__ __forceinline__ float bf2f(unsigned short u) {
  union { unsigned u; float f; } v; v.u = ((unsigned)u) << 16; return v.f;
}
__device__ __forceinline__ unsigned short f2bf(float f) {
  union { unsigned u; float f; } v; v.f = f;
  unsigned r = v.u + 0x7FFFu + ((v.u >> 16) & 1u);
  return (unsigned short)(r >> 16);
}

// ---------------- fp32 -> bf16 conversion ----------------
__global__ __launch_bounds__(256) void cvt_bf16_kernel(const float* __restrict__ in,
                                                       unsigned short* __restrict__ out,
                                                       int n4) {
  int i = blockIdx.x * blockDim.x + threadIdx.x;
  if (i < n4) {
    f32x4 v = ((const f32x4*)in)[i];
    ushort4 o;
    o.x = f2bf(v.x); o.y = f2bf(v.y); o.z = f2bf(v.z); o.w = f2bf(v.w);
    ((ushort4*)out)[i] = o;
  }
}

// ---------------- CSR build ----------------
__global__ void hist_kernel(const int* __restrict__ dst, int* __restrict__ deg,
                            int E, int N) {
  int i = blockIdx.x * blockDim.x + threadIdx.x;
  if (i < E) {
    int d = dst[i];
    if ((unsigned)d < (unsigned)N) atomicAdd(&deg[d], 1);
  }
}

__global__ __launch_bounds__(256) void scan_chunks(const int* __restrict__ deg,
                                                   int* __restrict__ excl,
                                                   int* __restrict__ csum, int N) {
  __shared__ int s[256];
  int t = threadIdx.x;
  int base = blockIdx.x * 1024 + t * 4;
  int v[4];
  int sum = 0;
#pragma unroll
  for (int i = 0; i < 4; ++i) {
    v[i] = (base + i < N) ? deg[base + i] : 0;
    sum += v[i];
  }
  s[t] = sum;
  __syncthreads();
  for (int off = 1; off < 256; off <<= 1) {
    int x = (t >= off) ? s[t - off] : 0;
    __syncthreads();
    s[t] += x;
    __syncthreads();
  }
  int run = s[t] - sum;
#pragma unroll
  for (int i = 0; i < 4; ++i) {
    if (base + i < N) excl[base + i] = run;
    run += v[i];
  }
  if (t == 255) csum[blockIdx.x] = s[255];
}

__global__ void scan_sums(int* __restrict__ csum, int nchunks) {
  if (threadIdx.x == 0 && blockIdx.x == 0) {
    int run = 0;
    for (int i = 0; i < nchunks; ++i) {
      int c = csum[i];
      csum[i] = run;
      run += c;
    }
  }
}

__global__ void finalize_rows(const int* __restrict__ excl, const int* __restrict__ csum,
                              int* __restrict__ row_start, int* __restrict__ cursor,
                              int N, int E) {
  int i = blockIdx.x * blockDim.x + threadIdx.x;
  if (i < N) {
    int v = excl[i] + csum[i >> 10];
    row_start[i] = v;
    cursor[i] = v;
  }
  if (i == 0) row_start[N] = E;
}

__global__ void scatter_kernel(const int* __restrict__ src, const int* __restrict__ dst,
                               int* __restrict__ cursor, int* __restrict__ sorted_src,
                               int* __restrict__ sorted_dst, int E, int N) {
  int i = blockIdx.x * blockDim.x + threadIdx.x;
  if (i < E) {
    int d = dst[i];
    int s = src[i];
    if ((unsigned)d < (unsigned)N) {
      int p = atomicAdd(&cursor[d], 1);
      if ((unsigned)p < (unsigned)E) {
        sorted_src[p] = ((unsigned)s < (unsigned)N) ? s : 0;
        sorted_dst[p] = d;
      }
    }
  }
}

// ---------------- GEMM: C = A(bf16,[M x 256]) * B(bf16,[ncols x 256])^T ----------------
template <int COLGROUPS, bool BF16OUT>
__global__ __launch_bounds__(256) void gemm_bt(const unsigned short* __restrict__ A,
                                               const unsigned short* __restrict__ B,
                                               float* __restrict__ Cf,
                                               unsigned short* __restrict__ Cb,
                                               const float* __restrict__ bias,
                                               int M) {
  const int K = 256;
  const int NCOL = COLGROUPS * 64;
  int wave = threadIdx.x >> 6;
  int lane = threadIdx.x & 63;
  int gw = blockIdx.x * 4 + wave;
  int rowTile = gw / COLGROUPS;
  int colGroup = gw % COLGROUPS;
  int row0 = rowTile * 16;
  if (row0 >= M) return;
  int col0 = colGroup * 64;
  int lr = lane & 15;
  int quad = lane >> 4;

  int arow = row0 + lr;
  if (arow >= M) arow = M - 1;
  const unsigned short* Ap = A + (size_t)arow * K + quad * 8;

  f32x4 acc[4] = {f32x4{0, 0, 0, 0}, f32x4{0, 0, 0, 0}, f32x4{0, 0, 0, 0},
                  f32x4{0, 0, 0, 0}};
#pragma unroll
  for (int kk = 0; kk < 8; ++kk) {
    short8 a = *(const short8*)(Ap + kk * 32);
#pragma unroll
    for (int t = 0; t < 4; ++t) {
      const unsigned short* Bp = B + (size_t)(col0 + 16 * t + lr) * K + quad * 8 + kk * 32;
      short8 b = *(const short8*)Bp;
      acc[t] = __builtin_amdgcn_mfma_f32_16x16x32_bf16(a, b, acc[t], 0, 0, 0);
    }
  }
#pragma unroll
  for (int t = 0; t < 4; ++t) {
#pragma unroll
    for (int r = 0; r < 4; ++r) {
      int row = row0 + quad * 4 + r;
      if (row < M) {
        int col = col0 + 16 * t + lr;
        float v = acc[t][r];
        if (BF16OUT) {
          Cb[(size_t)row * NCOL + col] = f2bf(v);
        } else {
          if (bias) v += bias[col];
          Cf[(size_t)row * NCOL + col] = v;
        }
      }
    }
  }
}

// ---------------- attention scores (bf16 h) ----------------
__global__ __launch_bounds__(256) void scores_kernel(const unsigned short* __restrict__ h,
                                                     const float* __restrict__ a_src,
                                                     const float* __restrict__ a_dst,
                                                     float* __restrict__ sS,
                                                     float* __restrict__ sD, int N) {
  __shared__ float As[FF], Ad[FF];
  int t = threadIdx.x;
  As[t] = a_src[t];
  Ad[t] = a_dst[t];
  __syncthreads();
  int g = blockIdx.x * 256 + t;
  if (g >= N * NHEAD) return;
  int n = g >> 2;
  int hh = g & 3;
  const ushort4* hp = (const ushort4*)(h + (size_t)n * FF + hh * HDIM);
  const float* ap = As + hh * HDIM;
  const float* dp = Ad + hh * HDIM;
  float ss = 0.f, sd = 0.f;
#pragma unroll
  for (int i = 0; i < 16; ++i) {
    ushort4 u = hp[i];
    float v0 = bf2f(u.x), v1 = bf2f(u.y), v2 = bf2f(u.z), v3 = bf2f(u.w);
    ss += v0 * ap[i * 4 + 0] + v1 * ap[i * 4 + 1] + v2 * ap[i * 4 + 2] + v3 * ap[i * 4 + 3];
    sd += v0 * dp[i * 4 + 0] + v1 * dp[i * 4 + 1] + v2 * dp[i * 4 + 2] + v3 * dp[i * 4 + 3];
  }
  sS[g] = ss;
  sD[g] = sd;
}

// ---------------- phase 1: per-(node,head) softmax stats (m clamped at 0, 1/l) ----------
__global__ __launch_bounds__(256) void softmax_stats_kernel(
    const float* __restrict__ sS, const float* __restrict__ sD,
    const int* __restrict__ row_start, const int* __restrict__ sorted_src,
    float* __restrict__ mbuf, float* __restrict__ linv, int N) {
  int g = blockIdx.x * 256 + threadIdx.x;
  if (g >= N * NHEAD) return;
  int n = g >> 2;
  int hh = g & 3;
  float sdv = sD[g];
  int jb = row_start[n];
  int je = row_start[n + 1];
  float m = 0.f, l = 0.f;
  for (int j = jb; j < je; ++j) {
    int s = sorted_src[j];
    float e = sS[s * NHEAD + hh] + sdv;
    e = (e >= 0.f) ? e : 0.2f * e;
    if (e <= m) {
      l += __expf(e - m);
    } else {
      l = l * __expf(m - e) + 1.f;
      m = e;
    }
  }
  mbuf[g] = m;
  linv[g] = 1.f / fmaxf(l, 1e-9f);
}

// ---------------- phase 1b: per-(edge,head) normalized weights ----------------
__global__ __launch_bounds__(256) void alpha_kernel(
    const float* __restrict__ sS, const float* __restrict__ sD,
    const float* __restrict__ mbuf, const float* __restrict__ linv,
    const int* __restrict__ sorted_src, const int* __restrict__ sorted_dst,
    float* __restrict__ alpha, int E4) {
  int g = blockIdx.x * 256 + threadIdx.x;
  if (g >= E4) return;
  int j = g >> 2;
  int hh = g & 3;
  int s = sorted_src[j];
  int d = sorted_dst[j];
  float e = sS[s * NHEAD + hh] + sD[d * NHEAD + hh];
  e = (e >= 0.f) ? e : 0.2f * e;
  alpha[g] = __expf(e - mbuf[d * NHEAD + hh]) * linv[d * NHEAD + hh];
}

// ---------------- phase 2: SpMM gather + BN + ELU, bf16 out ----------------
// One wave per node; lane covers features 4*lane..4*lane+3 (ushort4 = full 512B row/wave).
__global__ __launch_bounds__(256) void aggregate_kernel(
    const unsigned short* __restrict__ hprev, const float* __restrict__ alpha,
    const int* __restrict__ row_start, const int* __restrict__ sorted_src,
    const float* __restrict__ gamma, const float* __restrict__ beta,
    const float* __restrict__ mean, const float* __restrict__ var,
    unsigned short* __restrict__ hout, int N) {
  int wave = threadIdx.x >> 6;
  int lane = threadIdx.x & 63;
  int n = blockIdx.x * 4 + wave;
  if (n >= N) return;
  int hh = lane >> 4;        // head of this lane's 4 features
  int f0 = lane * 4;
  int jb = row_start[n];
  int je = row_start[n + 1];
  float o0 = 0.f, o1 = 0.f, o2 = 0.f, o3 = 0.f;
  int j = jb;
  for (; j + 3 < je; j += 4) {
    int s0 = sorted_src[j + 0];
    int s1 = sorted_src[j + 1];
    int s2 = sorted_src[j + 2];
    int s3 = sorted_src[j + 3];
    float a0 = alpha[(size_t)(j + 0) * NHEAD + hh];
    float a1 = alpha[(size_t)(j + 1) * NHEAD + hh];
    float a2 = alpha[(size_t)(j + 2) * NHEAD + hh];
    float a3 = alpha[(size_t)(j + 3) * NHEAD + hh];
    ushort4 u0 = *(const ushort4*)(hprev + (size_t)s0 * FF + f0);
    ushort4 u1 = *(const ushort4*)(hprev + (size_t)s1 * FF + f0);
    ushort4 u2 = *(const ushort4*)(hprev + (size_t)s2 * FF + f0);
    ushort4 u3 = *(const ushort4*)(hprev + (size_t)s3 * FF + f0);
    o0 += a0 * bf2f(u0.x) + a1 * bf2f(u1.x) + a2 * bf2f(u2.x) + a3 * bf2f(u3.x);
    o1 += a0 * bf2f(u0.y) + a1 * bf2f(u1.y) + a2 * bf2f(u2.y) + a3 * bf2f(u3.y);
    o2 += a0 * bf2f(u0.z) + a1 * bf2f(u1.z) + a2 * bf2f(u2.z) + a3 * bf2f(u3.z);
    o3 += a0 * bf2f(u0.w) + a1 * bf2f(u1.w) + a2 * bf2f(u2.w) + a3 * bf2f(u3.w);
  }
  for (; j < je; ++j) {
    int s = sorted_src[j];
    float a = alpha[(size_t)j * NHEAD + hh];
    ushort4 u = *(const ushort4*)(hprev + (size_t)s * FF + f0);
    o0 += a * bf2f(u.x);
    o1 += a * bf2f(u.y);
    o2 += a * bf2f(u.z);
    o3 += a * bf2f(u.w);
  }
  f32x4 g = *(const f32x4*)(gamma + f0);
  f32x4 b = *(const f32x4*)(beta + f0);
  f32x4 mu = *(const f32x4*)(mean + f0);
  f32x4 vr = *(const f32x4*)(var + f0);
  float v0 = (o0 - mu.x) * rsqrtf(vr.x + 1e-5f) * g.x + b.x;
  float v1 = (o1 - mu.y) * rsqrtf(vr.y + 1e-5f) * g.y + b.y;
  float v2 = (o2 - mu.z) * rsqrtf(vr.z + 1e-5f) * g.z + b.z;
  float v3 = (o3 - mu.w) * rsqrtf(vr.w + 1e-5f) * g.w + b.w;
  v0 = (v0 > 0.f) ? v0 : expm1f(v0);
  v1 = (v1 > 0.f) ? v1 : expm1f(v1);
  v2 = (v2 > 0.f) ? v2 : expm1f(v2);
  v3 = (v3 > 0.f) ? v3 : expm1f(v3);
  ushort4 ov;
  ov.x = f2bf(v0); ov.y = f2bf(v1); ov.z = f2bf(v2); ov.w = f2bf(v3);
  *(ushort4*)(hout + (size_t)n * FF + f0) = ov;
}

// ---------------- launch ----------------
extern "C" void kernel_launch(void* const* d_in, const int* in_sizes, int n_in,
                              void* d_out, int out_size, void* d_ws, size_t ws_size,
                              hipStream_t stream) {
  const float* x   = (const float*)d_in[0];
  const int* ei    = (const int*)d_in[1];
  const float* W1  = (const float*)d_in[2];
  const float* as1 = (const float*)d_in[3];
  const float* ad1 = (const float*)d_in[4];
  const float* g1  = (const float*)d_in[5];
  const float* b1  = (const float*)d_in[6];
  const float* m1  = (const float*)d_in[7];
  const float* v1  = (const float*)d_in[8];
  const float* W2  = (const float*)d_in[9];
  const float* as2 = (const float*)d_in[10];
  const float* ad2 = (const float*)d_in[11];
  const float* g2  = (const float*)d_in[12];
  const float* b2  = (const float*)d_in[13];
  const float* m2  = (const float*)d_in[14];
  const float* v2  = (const float*)d_in[15];
  const float* Wc  = (const float*)d_in[16];
  const float* bc  = (const float*)d_in[17];

  const int N = in_sizes[0] / FF;
  const int E = in_sizes[1] / 2;
  const int* srcIdx = ei;
  const int* dstIdx = ei + E;

  char* ws = (char*)d_ws;
  size_t off = 0;
  auto take = [&](size_t bytes) -> void* {
    void* p = ws + off;
    off += (bytes + 255) & ~(size_t)255;
    return p;
  };
  int* deg        = (int*)take((size_t)N * 4);
  int* excl       = (int*)take((size_t)N * 4);
  int* csum       = (int*)take(256 * 4);
  int* row_start  = (int*)take(((size_t)N + 1) * 4);
  int* cursor     = (int*)take((size_t)N * 4);
  int* sorted_src = (int*)take((size_t)E * 4);
  int* sorted_dst = (int*)take((size_t)E * 4);
  float* alpha    = (float*)take((size_t)E * NHEAD * 4);
  float* sS       = (float*)take((size_t)N * NHEAD * 4);
  float* sD       = (float*)take((size_t)N * NHEAD * 4);
  float* mbuf     = (float*)take((size_t)N * NHEAD * 4);
  float* linv     = (float*)take((size_t)N * NHEAD * 4);
  unsigned short* hpre = (unsigned short*)take((size_t)N * FF * 2);
  unsigned short* hact = (unsigned short*)take((size_t)N * FF * 2);
  unsigned short* xb   = (unsigned short*)take((size_t)N * FF * 2);
  unsigned short* w1b  = (unsigned short*)take((size_t)FF * FF * 2);
  unsigned short* w2b  = (unsigned short*)take((size_t)FF * FF * 2);
  unsigned short* wcb  = (unsigned short*)take((size_t)64 * FF * 2);

  const int tpb = 256;

  // dtype conversions
  {
    int n4 = (N * FF) / 4;
    cvt_bf16_kernel<<<(n4 + tpb - 1) / tpb, tpb, 0, stream>>>(x, xb, n4);
    int w4 = (FF * FF) / 4;
    cvt_bf16_kernel<<<(w4 + tpb - 1) / tpb, tpb, 0, stream>>>(W1, w1b, w4);
    cvt_bf16_kernel<<<(w4 + tpb - 1) / tpb, tpb, 0, stream>>>(W2, w2b, w4);
    int wc4 = (64 * FF) / 4;
    cvt_bf16_kernel<<<(wc4 + tpb - 1) / tpb, tpb, 0, stream>>>(Wc, wcb, wc4);
  }

  // CSR build (dst-sorted edge list), reused by both layers
  hipMemsetAsync(deg, 0, (size_t)N * 4, stream);
  hist_kernel<<<(E + tpb - 1) / tpb, tpb, 0, stream>>>(dstIdx, deg, E, N);
  int nchunks = (N + 1023) / 1024;
  scan_chunks<<<nchunks, 256, 0, stream>>>(deg, excl, csum, N);
  scan_sums<<<1, 64, 0, stream>>>(csum, nchunks);
  finalize_rows<<<(N + tpb - 1) / tpb, tpb, 0, stream>>>(excl, csum, row_start, cursor, N, E);
  scatter_kernel<<<(E + tpb - 1) / tpb, tpb, 0, stream>>>(srcIdx, dstIdx, cursor, sorted_src,
                                                          sorted_dst, E, N);

  int rowTiles = (N + 15) / 16;
  int nhBlocks = (N * NHEAD + tpb - 1) / tpb;
  int eaBlocks = (E * NHEAD + tpb - 1) / tpb;
  int aggBlocks = (N + 3) / 4;

  // layer 1
  gemm_bt<4, true><<<rowTiles, 256, 0, stream>>>(xb, w1b, (float*)nullptr, hpre,
                                                 (const float*)nullptr, N);
  scores_kernel<<<nhBlocks, tpb, 0, stream>>>(hpre, as1, ad1, sS, sD, N);
  softmax_stats_kernel<<<nhBlocks, tpb, 0, stream>>>(sS, sD, row_start, sorted_src, mbuf, linv, N);
  alpha_kernel<<<eaBlocks, tpb, 0, stream>>>(sS, sD, mbuf, linv, sorted_src, sorted_dst,
                                             alpha, E * NHEAD);
  aggregate_kernel<<<aggBlocks, 256, 0, stream>>>(hpre, alpha, row_start, sorted_src,
                                                  g1, b1, m1, v1, hact, N);
  // layer 2
  gemm_bt<4, true><<<rowTiles, 256, 0, stream>>>(hact, w2b, (float*)nullptr, hpre,
                                                 (const float*)nullptr, N);
  scores_kernel<<<nhBlocks, tpb, 0, stream>>>(hpre, as2, ad2, sS, sD, N);
  softmax_stats_kernel<<<nhBlocks, tpb, 0, stream>>>(sS, sD, row_start, sorted_src, mbuf, linv, N);
  alpha_kernel<<<eaBlocks, tpb, 0, stream>>>(sS, sD, mbuf, linv, sorted_src, sorted_dst,
                                             alpha, E * NHEAD);
  aggregate_kernel<<<aggBlocks, 256, 0, stream>>>(hpre, alpha, row_start, sorted_src,
                                                  g2, b2, m2, v2, hact, N);
  // classifier head -> fp32 out (+bias)
  gemm_bt<1, false><<<(rowTiles + 3) / 4, 256, 0, stream>>>(hact, wcb, (float*)d_out,
                                                            (unsigned short*)nullptr, bc, N);
}

// Round 5
// 429.900 us; speedup vs baseline: 1.4984x; 1.1139x over previous
//
#include <hip/hip_runtime.h>

typedef __attribute__((ext_vector_type(8))) short short8;
typedef __attribute__((ext_vector_type(4))) float f32x4;

#define FF 256   // hidden features
#define NHEAD 4
#define HDIM 64

__device__ __forceinline__ float bf2f(unsigned short u) {
  union { unsigned u; float f; } v; v.u = ((unsigned)u) << 16; return v.f;
}
__device__ __forceinline__ unsigned short f2bf(float f) {
  union { unsigned u; float f; } v; v.f = f;
  unsigned r = v.u + 0x7FFFu + ((v.u >> 16) & 1u);
  return (unsigned short)(r >> 16);
}

// ---------------- fp32 -> bf16 conversion ----------------
__global__ __launch_bounds__(256) void cvt_bf16_kernel(const float* __restrict__ in,
                                                       unsigned short* __restrict__ out,
                                                       int n4) {
  int i = blockIdx.x * blockDim.x + threadIdx.x;
  if (i < n4) {
    f32x4 v = ((const f32x4*)in)[i];
    ushort4 o;
    o.x = f2bf(v.x); o.y = f2bf(v.y); o.z = f2bf(v.z); o.w = f2bf(v.w);
    ((ushort4*)out)[i] = o;
  }
}

// ---------------- CSR build ----------------
__global__ void hist_kernel(const int* __restrict__ dst, int* __restrict__ deg,
                            int E, int N) {
  int i = blockIdx.x * blockDim.x + threadIdx.x;
  if (i < E) {
    int d = dst[i];
    if ((unsigned)d < (unsigned)N) atomicAdd(&deg[d], 1);
  }
}

__global__ __launch_bounds__(256) void scan_chunks(const int* __restrict__ deg,
                                                   int* __restrict__ excl,
                                                   int* __restrict__ csum, int N) {
  __shared__ int s[256];
  int t = threadIdx.x;
  int base = blockIdx.x * 1024 + t * 4;
  int v[4];
  int sum = 0;
#pragma unroll
  for (int i = 0; i < 4; ++i) {
    v[i] = (base + i < N) ? deg[base + i] : 0;
    sum += v[i];
  }
  s[t] = sum;
  __syncthreads();
  for (int off = 1; off < 256; off <<= 1) {
    int x = (t >= off) ? s[t - off] : 0;
    __syncthreads();
    s[t] += x;
    __syncthreads();
  }
  int run = s[t] - sum;
#pragma unroll
  for (int i = 0; i < 4; ++i) {
    if (base + i < N) excl[base + i] = run;
    run += v[i];
  }
  if (t == 255) csum[blockIdx.x] = s[255];
}

__global__ void scan_sums(int* __restrict__ csum, int nchunks) {
  if (threadIdx.x == 0 && blockIdx.x == 0) {
    int run = 0;
    for (int i = 0; i < nchunks; ++i) {
      int c = csum[i];
      csum[i] = run;
      run += c;
    }
  }
}

__global__ void finalize_rows(const int* __restrict__ excl, const int* __restrict__ csum,
                              int* __restrict__ row_start, int* __restrict__ cursor,
                              int N, int E) {
  int i = blockIdx.x * blockDim.x + threadIdx.x;
  if (i < N) {
    int v = excl[i] + csum[i >> 10];
    row_start[i] = v;
    cursor[i] = v;
  }
  if (i == 0) row_start[N] = E;
}

__global__ void scatter_kernel(const int* __restrict__ src, const int* __restrict__ dst,
                               int* __restrict__ cursor, int* __restrict__ sorted_src,
                               int* __restrict__ sorted_dst, int E, int N) {
  int i = blockIdx.x * blockDim.x + threadIdx.x;
  if (i < E) {
    int d = dst[i];
    int s = src[i];
    if ((unsigned)d < (unsigned)N) {
      int p = atomicAdd(&cursor[d], 1);
      if ((unsigned)p < (unsigned)E) {
        sorted_src[p] = ((unsigned)s < (unsigned)N) ? s : 0;
        sorted_dst[p] = d;
      }
    }
  }
}

// ---------------- GEMM v2: C = A(bf16,[M x 256]) * B(bf16,[ncols x 256])^T ----------------
// Each wave computes 64 rows x 64 cols (4 row-subtiles x 4 col-tiles of 16x16),
// MFMA:load ratio 2:1 (was 0.8:1). COLGROUPS=4: block = 64 rows x 256 cols, wave=colgroup.
// COLGROUPS=1 (head): block = 256 rows x 64 cols, wave=row chunk.
template <int COLGROUPS, bool BF16OUT>
__global__ __launch_bounds__(256) void gemm_bt(const unsigned short* __restrict__ A,
                                               const unsigned short* __restrict__ B,
                                               float* __restrict__ Cf,
                                               unsigned short* __restrict__ Cb,
                                               const float* __restrict__ bias,
                                               int M) {
  const int K = 256;
  const int NCOL = COLGROUPS * 64;
  int wave = threadIdx.x >> 6;
  int lane = threadIdx.x & 63;
  int row0w, col0;
  if (COLGROUPS == 4) {
    row0w = blockIdx.x * 64;
    col0 = wave * 64;
  } else {
    row0w = blockIdx.x * 256 + wave * 64;
    col0 = 0;
  }
  if (row0w >= M) return;
  int lr = lane & 15;
  int quad = lane >> 4;

  const unsigned short* Aps[4];
#pragma unroll
  for (int rt = 0; rt < 4; ++rt) {
    int arow = row0w + rt * 16 + lr;
    if (arow >= M) arow = M - 1;
    Aps[rt] = A + (size_t)arow * K + quad * 8;
  }
  const unsigned short* Bp0 = B + (size_t)(col0 + lr) * K + quad * 8;

  f32x4 acc[4][4];
#pragma unroll
  for (int rt = 0; rt < 4; ++rt)
#pragma unroll
    for (int t = 0; t < 4; ++t) acc[rt][t] = f32x4{0, 0, 0, 0};

#pragma unroll
  for (int kk = 0; kk < 8; ++kk) {
    short8 a[4], b[4];
#pragma unroll
    for (int rt = 0; rt < 4; ++rt) a[rt] = *(const short8*)(Aps[rt] + kk * 32);
#pragma unroll
    for (int t = 0; t < 4; ++t) b[t] = *(const short8*)(Bp0 + (size_t)(16 * t) * K + kk * 32);
#pragma unroll
    for (int rt = 0; rt < 4; ++rt)
#pragma unroll
      for (int t = 0; t < 4; ++t)
        acc[rt][t] = __builtin_amdgcn_mfma_f32_16x16x32_bf16(a[rt], b[t], acc[rt][t], 0, 0, 0);
  }

#pragma unroll
  for (int rt = 0; rt < 4; ++rt) {
#pragma unroll
    for (int t = 0; t < 4; ++t) {
#pragma unroll
      for (int r = 0; r < 4; ++r) {
        int row = row0w + rt * 16 + quad * 4 + r;
        if (row < M) {
          int col = col0 + 16 * t + lr;
          float v = acc[rt][t][r];
          if (BF16OUT) {
            Cb[(size_t)row * NCOL + col] = f2bf(v);
          } else {
            if (bias) v += bias[col];
            Cf[(size_t)row * NCOL + col] = v;
          }
        }
      }
    }
  }
}

// ---------------- attention scores (bf16 h) ----------------
__global__ __launch_bounds__(256) void scores_kernel(const unsigned short* __restrict__ h,
                                                     const float* __restrict__ a_src,
                                                     const float* __restrict__ a_dst,
                                                     float* __restrict__ sS,
                                                     float* __restrict__ sD, int N) {
  __shared__ float As[FF], Ad[FF];
  int t = threadIdx.x;
  As[t] = a_src[t];
  Ad[t] = a_dst[t];
  __syncthreads();
  int g = blockIdx.x * 256 + t;
  if (g >= N * NHEAD) return;
  int n = g >> 2;
  int hh = g & 3;
  const ushort4* hp = (const ushort4*)(h + (size_t)n * FF + hh * HDIM);
  const float* ap = As + hh * HDIM;
  const float* dp = Ad + hh * HDIM;
  float ss = 0.f, sd = 0.f;
#pragma unroll
  for (int i = 0; i < 16; ++i) {
    ushort4 u = hp[i];
    float v0 = bf2f(u.x), v1 = bf2f(u.y), v2 = bf2f(u.z), v3 = bf2f(u.w);
    ss += v0 * ap[i * 4 + 0] + v1 * ap[i * 4 + 1] + v2 * ap[i * 4 + 2] + v3 * ap[i * 4 + 3];
    sd += v0 * dp[i * 4 + 0] + v1 * dp[i * 4 + 1] + v2 * dp[i * 4 + 2] + v3 * dp[i * 4 + 3];
  }
  sS[g] = ss;
  sD[g] = sd;
}

// ---------------- phase 1: per-(node,head) softmax stats (m clamped at 0, 1/l) ----------
__global__ __launch_bounds__(256) void softmax_stats_kernel(
    const float* __restrict__ sS, const float* __restrict__ sD,
    const int* __restrict__ row_start, const int* __restrict__ sorted_src,
    float* __restrict__ mbuf, float* __restrict__ linv, int N) {
  int g = blockIdx.x * 256 + threadIdx.x;
  if (g >= N * NHEAD) return;
  int n = g >> 2;
  int hh = g & 3;
  float sdv = sD[g];
  int jb = row_start[n];
  int je = row_start[n + 1];
  float m = 0.f, l = 0.f;
  for (int j = jb; j < je; ++j) {
    int s = sorted_src[j];
    float e = sS[s * NHEAD + hh] + sdv;
    e = (e >= 0.f) ? e : 0.2f * e;
    if (e <= m) {
      l += __expf(e - m);
    } else {
      l = l * __expf(m - e) + 1.f;
      m = e;
    }
  }
  mbuf[g] = m;
  linv[g] = 1.f / fmaxf(l, 1e-9f);
}

// ---------------- phase 1b: per-(edge,head) normalized weights ----------------
__global__ __launch_bounds__(256) void alpha_kernel(
    const float* __restrict__ sS, const float* __restrict__ sD,
    const float* __restrict__ mbuf, const float* __restrict__ linv,
    const int* __restrict__ sorted_src, const int* __restrict__ sorted_dst,
    float* __restrict__ alpha, int E4) {
  int g = blockIdx.x * 256 + threadIdx.x;
  if (g >= E4) return;
  int j = g >> 2;
  int hh = g & 3;
  int s = sorted_src[j];
  int d = sorted_dst[j];
  float e = sS[s * NHEAD + hh] + sD[d * NHEAD + hh];
  e = (e >= 0.f) ? e : 0.2f * e;
  alpha[g] = __expf(e - mbuf[d * NHEAD + hh]) * linv[d * NHEAD + hh];
}

// ---------------- phase 2: SpMM gather + BN + ELU, bf16 out ----------------
__global__ __launch_bounds__(256) void aggregate_kernel(
    const unsigned short* __restrict__ hprev, const float* __restrict__ alpha,
    const int* __restrict__ row_start, const int* __restrict__ sorted_src,
    const float* __restrict__ gamma, const float* __restrict__ beta,
    const float* __restrict__ mean, const float* __restrict__ var,
    unsigned short* __restrict__ hout, int N) {
  int wave = threadIdx.x >> 6;
  int lane = threadIdx.x & 63;
  int n = blockIdx.x * 4 + wave;
  if (n >= N) return;
  int hh = lane >> 4;
  int f0 = lane * 4;
  int jb = row_start[n];
  int je = row_start[n + 1];
  float o0 = 0.f, o1 = 0.f, o2 = 0.f, o3 = 0.f;
  int j = jb;
  for (; j + 3 < je; j += 4) {
    int s0 = sorted_src[j + 0];
    int s1 = sorted_src[j + 1];
    int s2 = sorted_src[j + 2];
    int s3 = sorted_src[j + 3];
    float a0 = alpha[(size_t)(j + 0) * NHEAD + hh];
    float a1 = alpha[(size_t)(j + 1) * NHEAD + hh];
    float a2 = alpha[(size_t)(j + 2) * NHEAD + hh];
    float a3 = alpha[(size_t)(j + 3) * NHEAD + hh];
    ushort4 u0 = *(const ushort4*)(hprev + (size_t)s0 * FF + f0);
    ushort4 u1 = *(const ushort4*)(hprev + (size_t)s1 * FF + f0);
    ushort4 u2 = *(const ushort4*)(hprev + (size_t)s2 * FF + f0);
    ushort4 u3 = *(const ushort4*)(hprev + (size_t)s3 * FF + f0);
    o0 += a0 * bf2f(u0.x) + a1 * bf2f(u1.x) + a2 * bf2f(u2.x) + a3 * bf2f(u3.x);
    o1 += a0 * bf2f(u0.y) + a1 * bf2f(u1.y) + a2 * bf2f(u2.y) + a3 * bf2f(u3.y);
    o2 += a0 * bf2f(u0.z) + a1 * bf2f(u1.z) + a2 * bf2f(u2.z) + a3 * bf2f(u3.z);
    o3 += a0 * bf2f(u0.w) + a1 * bf2f(u1.w) + a2 * bf2f(u2.w) + a3 * bf2f(u3.w);
  }
  for (; j < je; ++j) {
    int s = sorted_src[j];
    float a = alpha[(size_t)j * NHEAD + hh];
    ushort4 u = *(const ushort4*)(hprev + (size_t)s * FF + f0);
    o0 += a * bf2f(u.x);
    o1 += a * bf2f(u.y);
    o2 += a * bf2f(u.z);
    o3 += a * bf2f(u.w);
  }
  f32x4 g = *(const f32x4*)(gamma + f0);
  f32x4 b = *(const f32x4*)(beta + f0);
  f32x4 mu = *(const f32x4*)(mean + f0);
  f32x4 vr = *(const f32x4*)(var + f0);
  float v0 = (o0 - mu.x) * rsqrtf(vr.x + 1e-5f) * g.x + b.x;
  float v1 = (o1 - mu.y) * rsqrtf(vr.y + 1e-5f) * g.y + b.y;
  float v2 = (o2 - mu.z) * rsqrtf(vr.z + 1e-5f) * g.z + b.z;
  float v3 = (o3 - mu.w) * rsqrtf(vr.w + 1e-5f) * g.w + b.w;
  v0 = (v0 > 0.f) ? v0 : expm1f(v0);
  v1 = (v1 > 0.f) ? v1 : expm1f(v1);
  v2 = (v2 > 0.f) ? v2 : expm1f(v2);
  v3 = (v3 > 0.f) ? v3 : expm1f(v3);
  ushort4 ov;
  ov.x = f2bf(v0); ov.y = f2bf(v1); ov.z = f2bf(v2); ov.w = f2bf(v3);
  *(ushort4*)(hout + (size_t)n * FF + f0) = ov;
}

// ---------------- launch ----------------
extern "C" void kernel_launch(void* const* d_in, const int* in_sizes, int n_in,
                              void* d_out, int out_size, void* d_ws, size_t ws_size,
                              hipStream_t stream) {
  const float* x   = (const float*)d_in[0];
  const int* ei    = (const int*)d_in[1];
  const float* W1  = (const float*)d_in[2];
  const float* as1 = (const float*)d_in[3];
  const float* ad1 = (const float*)d_in[4];
  const float* g1  = (const float*)d_in[5];
  const float* b1  = (const float*)d_in[6];
  const float* m1  = (const float*)d_in[7];
  const float* v1  = (const float*)d_in[8];
  const float* W2  = (const float*)d_in[9];
  const float* as2 = (const float*)d_in[10];
  const float* ad2 = (const float*)d_in[11];
  const float* g2  = (const float*)d_in[12];
  const float* b2  = (const float*)d_in[13];
  const float* m2  = (const float*)d_in[14];
  const float* v2  = (const float*)d_in[15];
  const float* Wc  = (const float*)d_in[16];
  const float* bc  = (const float*)d_in[17];

  const int N = in_sizes[0] / FF;
  const int E = in_sizes[1] / 2;
  const int* srcIdx = ei;
  const int* dstIdx = ei + E;

  char* ws = (char*)d_ws;
  size_t off = 0;
  auto take = [&](size_t bytes) -> void* {
    void* p = ws + off;
    off += (bytes + 255) & ~(size_t)255;
    return p;
  };
  int* deg        = (int*)take((size_t)N * 4);
  int* excl       = (int*)take((size_t)N * 4);
  int* csum       = (int*)take(256 * 4);
  int* row_start  = (int*)take(((size_t)N + 1) * 4);
  int* cursor     = (int*)take((size_t)N * 4);
  int* sorted_src = (int*)take((size_t)E * 4);
  int* sorted_dst = (int*)take((size_t)E * 4);
  float* alpha    = (float*)take((size_t)E * NHEAD * 4);
  float* sS       = (float*)take((size_t)N * NHEAD * 4);
  float* sD       = (float*)take((size_t)N * NHEAD * 4);
  float* mbuf     = (float*)take((size_t)N * NHEAD * 4);
  float* linv     = (float*)take((size_t)N * NHEAD * 4);
  unsigned short* hpre = (unsigned short*)take((size_t)N * FF * 2);
  unsigned short* hact = (unsigned short*)take((size_t)N * FF * 2);
  unsigned short* xb   = (unsigned short*)take((size_t)N * FF * 2);
  unsigned short* w1b  = (unsigned short*)take((size_t)FF * FF * 2);
  unsigned short* w2b  = (unsigned short*)take((size_t)FF * FF * 2);
  unsigned short* wcb  = (unsigned short*)take((size_t)64 * FF * 2);

  const int tpb = 256;

  // dtype conversions
  {
    int n4 = (N * FF) / 4;
    cvt_bf16_kernel<<<(n4 + tpb - 1) / tpb, tpb, 0, stream>>>(x, xb, n4);
    int w4 = (FF * FF) / 4;
    cvt_bf16_kernel<<<(w4 + tpb - 1) / tpb, tpb, 0, stream>>>(W1, w1b, w4);
    cvt_bf16_kernel<<<(w4 + tpb - 1) / tpb, tpb, 0, stream>>>(W2, w2b, w4);
    int wc4 = (64 * FF) / 4;
    cvt_bf16_kernel<<<(wc4 + tpb - 1) / tpb, tpb, 0, stream>>>(Wc, wcb, wc4);
  }

  // CSR build (dst-sorted edge list), reused by both layers
  hipMemsetAsync(deg, 0, (size_t)N * 4, stream);
  hist_kernel<<<(E + tpb - 1) / tpb, tpb, 0, stream>>>(dstIdx, deg, E, N);
  int nchunks = (N + 1023) / 1024;
  scan_chunks<<<nchunks, 256, 0, stream>>>(deg, excl, csum, N);
  scan_sums<<<1, 64, 0, stream>>>(csum, nchunks);
  finalize_rows<<<(N + tpb - 1) / tpb, tpb, 0, stream>>>(excl, csum, row_start, cursor, N, E);
  scatter_kernel<<<(E + tpb - 1) / tpb, tpb, 0, stream>>>(srcIdx, dstIdx, cursor, sorted_src,
                                                          sorted_dst, E, N);

  int nhBlocks = (N * NHEAD + tpb - 1) / tpb;
  int eaBlocks = (E * NHEAD + tpb - 1) / tpb;
  int aggBlocks = (N + 3) / 4;
  int gemmBlocks = (N + 63) / 64;        // 64 rows/block, 256 cols
  int headBlocks = (N + 255) / 256;      // 256 rows/block, 64 cols

  // layer 1
  gemm_bt<4, true><<<gemmBlocks, 256, 0, stream>>>(xb, w1b, (float*)nullptr, hpre,
                                                   (const float*)nullptr, N);
  scores_kernel<<<nhBlocks, tpb, 0, stream>>>(hpre, as1, ad1, sS, sD, N);
  softmax_stats_kernel<<<nhBlocks, tpb, 0, stream>>>(sS, sD, row_start, sorted_src, mbuf, linv, N);
  alpha_kernel<<<eaBlocks, tpb, 0, stream>>>(sS, sD, mbuf, linv, sorted_src, sorted_dst,
                                             alpha, E * NHEAD);
  aggregate_kernel<<<aggBlocks, 256, 0, stream>>>(hpre, alpha, row_start, sorted_src,
                                                  g1, b1, m1, v1, hact, N);
  // layer 2
  gemm_bt<4, true><<<gemmBlocks, 256, 0, stream>>>(hact, w2b, (float*)nullptr, hpre,
                                                   (const float*)nullptr, N);
  scores_kernel<<<nhBlocks, tpb, 0, stream>>>(hpre, as2, ad2, sS, sD, N);
  softmax_stats_kernel<<<nhBlocks, tpb, 0, stream>>>(sS, sD, row_start, sorted_src, mbuf, linv, N);
  alpha_kernel<<<eaBlocks, tpb, 0, stream>>>(sS, sD, mbuf, linv, sorted_src, sorted_dst,
                                             alpha, E * NHEAD);
  aggregate_kernel<<<aggBlocks, 256, 0, stream>>>(hpre, alpha, row_start, sorted_src,
                                                  g2, b2, m2, v2, hact, N);
  // classifier head -> fp32 out (+bias)
  gemm_bt<1, false><<<headBlocks, 256, 0, stream>>>(hact, wcb, (float*)d_out,
                                                    (unsigned short*)nullptr, bc, N);
}

// Round 6
// 417.711 us; speedup vs baseline: 1.5421x; 1.0292x over previous
//
#include <hip/hip_runtime.h>

typedef __attribute__((ext_vector_type(8))) short short8;
typedef __attribute__((ext_vector_type(4))) float f32x4;

#define FF 256   // hidden features
#define NHEAD 4
#define HDIM 64

__device__ __forceinline__ float bf2f(unsigned short u) {
  union { unsigned u; float f; } v; v.u = ((unsigned)u) << 16; return v.f;
}
__device__ __forceinline__ unsigned short f2bf(float f) {
  union { unsigned u; float f; } v; v.f = f;
  unsigned r = v.u + 0x7FFFu + ((v.u >> 16) & 1u);
  return (unsigned short)(r >> 16);
}

// ---------------- fused fp32 -> bf16 conversion (4 segments, 1 dispatch) ----------------
__global__ __launch_bounds__(256) void cvt4_kernel(
    const float* __restrict__ p0, int n0, const float* __restrict__ p1, int n1,
    const float* __restrict__ p2, int n2, const float* __restrict__ p3, int n3,
    unsigned short* __restrict__ o0, unsigned short* __restrict__ o1,
    unsigned short* __restrict__ o2, unsigned short* __restrict__ o3) {
  int i = blockIdx.x * 256 + threadIdx.x;
  const float* in;
  unsigned short* out;
  int idx;
  if (i < n0) { in = p0; out = o0; idx = i; }
  else if (i < n0 + n1) { in = p1; out = o1; idx = i - n0; }
  else if (i < n0 + n1 + n2) { in = p2; out = o2; idx = i - n0 - n1; }
  else if (i < n0 + n1 + n2 + n3) { in = p3; out = o3; idx = i - n0 - n1 - n2; }
  else return;
  f32x4 v = ((const f32x4*)in)[idx];
  ushort4 o;
  o.x = f2bf(v.x); o.y = f2bf(v.y); o.z = f2bf(v.z); o.w = f2bf(v.w);
  ((ushort4*)out)[idx] = o;
}

// ---------------- CSR build ----------------
__global__ void hist_kernel(const int* __restrict__ dst, int* __restrict__ deg,
                            int E, int N) {
  int i = blockIdx.x * blockDim.x + threadIdx.x;
  if (i < E) {
    int d = dst[i];
    if ((unsigned)d < (unsigned)N) atomicAdd(&deg[d], 1);
  }
}

__global__ __launch_bounds__(256) void scan_chunks(const int* __restrict__ deg,
                                                   int* __restrict__ excl,
                                                   int* __restrict__ csum, int N) {
  __shared__ int s[256];
  int t = threadIdx.x;
  int base = blockIdx.x * 1024 + t * 4;
  int v[4];
  int sum = 0;
#pragma unroll
  for (int i = 0; i < 4; ++i) {
    v[i] = (base + i < N) ? deg[base + i] : 0;
    sum += v[i];
  }
  s[t] = sum;
  __syncthreads();
  for (int off = 1; off < 256; off <<= 1) {
    int x = (t >= off) ? s[t - off] : 0;
    __syncthreads();
    s[t] += x;
    __syncthreads();
  }
  int run = s[t] - sum;
#pragma unroll
  for (int i = 0; i < 4; ++i) {
    if (base + i < N) excl[base + i] = run;
    run += v[i];
  }
  if (t == 255) csum[blockIdx.x] = s[255];
}

__global__ void scan_sums(int* __restrict__ csum, int nchunks) {
  if (threadIdx.x == 0 && blockIdx.x == 0) {
    int run = 0;
    for (int i = 0; i < nchunks; ++i) {
      int c = csum[i];
      csum[i] = run;
      run += c;
    }
  }
}

__global__ void finalize_rows(const int* __restrict__ excl, const int* __restrict__ csum,
                              int* __restrict__ row_start, int* __restrict__ cursor,
                              int N, int E) {
  int i = blockIdx.x * blockDim.x + threadIdx.x;
  if (i < N) {
    int v = excl[i] + csum[i >> 10];
    row_start[i] = v;
    cursor[i] = v;
  }
  if (i == 0) row_start[N] = E;
}

__global__ void scatter_kernel(const int* __restrict__ src, const int* __restrict__ dst,
                               int* __restrict__ cursor, int* __restrict__ sorted_src,
                               int E, int N) {
  int i = blockIdx.x * blockDim.x + threadIdx.x;
  if (i < E) {
    int d = dst[i];
    int s = src[i];
    if ((unsigned)d < (unsigned)N) {
      int p = atomicAdd(&cursor[d], 1);
      if ((unsigned)p < (unsigned)E)
        sorted_src[p] = ((unsigned)s < (unsigned)N) ? s : 0;
    }
  }
}

// ---------------- GEMM: C = A(bf16,[M x 256]) * B(bf16,[ncols x 256])^T ----------------
// Wave computes 64 rows x 64 cols. COLGROUPS=4: wave's col span = one head; SCORES
// fuses s_src/s_dst (per-row dot with a_src/a_dst + quad-local shfl reduction).
template <int COLGROUPS, bool BF16OUT, bool SCORES>
__global__ __launch_bounds__(256) void gemm_bt(const unsigned short* __restrict__ A,
                                               const unsigned short* __restrict__ B,
                                               float* __restrict__ Cf,
                                               unsigned short* __restrict__ Cb,
                                               const float* __restrict__ bias,
                                               const float* __restrict__ a_src,
                                               const float* __restrict__ a_dst,
                                               float* __restrict__ sS,
                                               float* __restrict__ sD,
                                               int M) {
  const int K = 256;
  const int NCOL = COLGROUPS * 64;
  int wave = threadIdx.x >> 6;
  int lane = threadIdx.x & 63;
  int row0w, col0;
  if (COLGROUPS == 4) {
    row0w = blockIdx.x * 64;
    col0 = wave * 64;
  } else {
    row0w = blockIdx.x * 256 + wave * 64;
    col0 = 0;
  }
  if (row0w >= M) return;
  int lr = lane & 15;
  int quad = lane >> 4;

  const unsigned short* Aps[4];
#pragma unroll
  for (int rt = 0; rt < 4; ++rt) {
    int arow = row0w + rt * 16 + lr;
    if (arow >= M) arow = M - 1;
    Aps[rt] = A + (size_t)arow * K + quad * 8;
  }
  const unsigned short* Bp0 = B + (size_t)(col0 + lr) * K + quad * 8;

  f32x4 acc[4][4];
#pragma unroll
  for (int rt = 0; rt < 4; ++rt)
#pragma unroll
    for (int t = 0; t < 4; ++t) acc[rt][t] = f32x4{0, 0, 0, 0};

#pragma unroll
  for (int kk = 0; kk < 8; ++kk) {
    short8 a[4], b[4];
#pragma unroll
    for (int rt = 0; rt < 4; ++rt) a[rt] = *(const short8*)(Aps[rt] + kk * 32);
#pragma unroll
    for (int t = 0; t < 4; ++t) b[t] = *(const short8*)(Bp0 + (size_t)(16 * t) * K + kk * 32);
#pragma unroll
    for (int rt = 0; rt < 4; ++rt)
#pragma unroll
      for (int t = 0; t < 4; ++t)
        acc[rt][t] = __builtin_amdgcn_mfma_f32_16x16x32_bf16(a[rt], b[t], acc[rt][t], 0, 0, 0);
  }

#pragma unroll
  for (int rt = 0; rt < 4; ++rt) {
#pragma unroll
    for (int t = 0; t < 4; ++t) {
#pragma unroll
      for (int r = 0; r < 4; ++r) {
        int row = row0w + rt * 16 + quad * 4 + r;
        if (row < M) {
          int col = col0 + 16 * t + lr;
          float v = acc[rt][t][r];
          if (BF16OUT) {
            Cb[(size_t)row * NCOL + col] = f2bf(v);
          } else {
            if (bias) v += bias[col];
            Cf[(size_t)row * NCOL + col] = v;
          }
        }
      }
    }
  }

  if (SCORES) {
    // wave's head = wave; per-row dot over this head's 64 dims, quad-local reduce.
    float asv[4], adv[4];
#pragma unroll
    for (int t = 0; t < 4; ++t) {
      asv[t] = a_src[col0 + 16 * t + lr];
      adv[t] = a_dst[col0 + 16 * t + lr];
    }
#pragma unroll
    for (int rt = 0; rt < 4; ++rt) {
#pragma unroll
      for (int r = 0; r < 4; ++r) {
        float ps = acc[rt][0][r] * asv[0] + acc[rt][1][r] * asv[1] +
                   acc[rt][2][r] * asv[2] + acc[rt][3][r] * asv[3];
        float pd = acc[rt][0][r] * adv[0] + acc[rt][1][r] * adv[1] +
                   acc[rt][2][r] * adv[2] + acc[rt][3][r] * adv[3];
#pragma unroll
        for (int sft = 1; sft < 16; sft <<= 1) {
          ps += __shfl_xor(ps, sft);
          pd += __shfl_xor(pd, sft);
        }
        if (lr == 0) {
          int row = row0w + rt * 16 + quad * 4 + r;
          if (row < M) {
            sS[row * NHEAD + wave] = ps;
            sD[row * NHEAD + wave] = pd;
          }
        }
      }
    }
  }
}

// ---------------- fused softmax stats + per-(edge,head) alpha ----------------
__global__ __launch_bounds__(256) void stats_alpha_kernel(
    const float* __restrict__ sS, const float* __restrict__ sD,
    const int* __restrict__ row_start, const int* __restrict__ sorted_src,
    float* __restrict__ alpha, int N) {
  int g = blockIdx.x * 256 + threadIdx.x;
  if (g >= N * NHEAD) return;
  int n = g >> 2;
  int hh = g & 3;
  float sdv = sD[g];
  int jb = row_start[n];
  int je = row_start[n + 1];
  float m = 0.f, l = 0.f;
  for (int j = jb; j < je; ++j) {
    int s = sorted_src[j];
    float e = sS[s * NHEAD + hh] + sdv;
    e = (e >= 0.f) ? e : 0.2f * e;
    if (e <= m) {
      l += __expf(e - m);
    } else {
      l = l * __expf(m - e) + 1.f;
      m = e;
    }
  }
  float li = 1.f / fmaxf(l, 1e-9f);
  for (int j = jb; j < je; ++j) {
    int s = sorted_src[j];
    float e = sS[s * NHEAD + hh] + sdv;
    e = (e >= 0.f) ? e : 0.2f * e;
    alpha[(size_t)j * NHEAD + hh] = __expf(e - m) * li;
  }
}

// ---------------- SpMM gather + BN + ELU, bf16 out ----------------
// One wave per node; half-wave covers a full 512B row (16B/lane short8), so 2 edges
// stream per wave-iteration; unroll 2 -> 4 row-gathers in flight.
__global__ __launch_bounds__(256) void aggregate_kernel(
    const unsigned short* __restrict__ hprev, const float* __restrict__ alpha,
    const int* __restrict__ row_start, const int* __restrict__ sorted_src,
    const float* __restrict__ gamma, const float* __restrict__ beta,
    const float* __restrict__ mean, const float* __restrict__ var,
    unsigned short* __restrict__ hout, int N) {
  int wave = threadIdx.x >> 6;
  int lane = threadIdx.x & 63;
  int n = blockIdx.x * 4 + wave;
  if (n >= N) return;
  int half = lane >> 5;
  int ll = lane & 31;
  int hh = ll >> 3;          // 8 lanes per head chunk
  int f0 = ll * 8;           // 8 features per lane
  int jb = row_start[n];
  int je = row_start[n + 1];
  float o[8];
#pragma unroll
  for (int k = 0; k < 8; ++k) o[k] = 0.f;

  int j = jb + half;
  for (; j + 2 < je; j += 4) {
    int s0 = sorted_src[j];
    int s1 = sorted_src[j + 2];
    float a0 = alpha[(size_t)j * NHEAD + hh];
    float a1 = alpha[(size_t)(j + 2) * NHEAD + hh];
    short8 u0 = *(const short8*)(hprev + (size_t)s0 * FF + f0);
    short8 u1 = *(const short8*)(hprev + (size_t)s1 * FF + f0);
#pragma unroll
    for (int k = 0; k < 8; ++k)
      o[k] += a0 * bf2f((unsigned short)u0[k]) + a1 * bf2f((unsigned short)u1[k]);
  }
  if (j < je) {
    int s = sorted_src[j];
    float a = alpha[(size_t)j * NHEAD + hh];
    short8 u = *(const short8*)(hprev + (size_t)s * FF + f0);
#pragma unroll
    for (int k = 0; k < 8; ++k) o[k] += a * bf2f((unsigned short)u[k]);
  }

  // combine the two half-wave partial sums (same features, different edges)
#pragma unroll
  for (int k = 0; k < 8; ++k) o[k] += __shfl_xor(o[k], 32);

  if (half == 0) {
    f32x4 g0 = *(const f32x4*)(gamma + f0);
    f32x4 g1 = *(const f32x4*)(gamma + f0 + 4);
    f32x4 b0 = *(const f32x4*)(beta + f0);
    f32x4 b1 = *(const f32x4*)(beta + f0 + 4);
    f32x4 mu0 = *(const f32x4*)(mean + f0);
    f32x4 mu1 = *(const f32x4*)(mean + f0 + 4);
    f32x4 vr0 = *(const f32x4*)(var + f0);
    f32x4 vr1 = *(const f32x4*)(var + f0 + 4);
    float gg[8] = {g0.x, g0.y, g0.z, g0.w, g1.x, g1.y, g1.z, g1.w};
    float bb[8] = {b0.x, b0.y, b0.z, b0.w, b1.x, b1.y, b1.z, b1.w};
    float mm[8] = {mu0.x, mu0.y, mu0.z, mu0.w, mu1.x, mu1.y, mu1.z, mu1.w};
    float vv[8] = {vr0.x, vr0.y, vr0.z, vr0.w, vr1.x, vr1.y, vr1.z, vr1.w};
    short8 ov;
#pragma unroll
    for (int k = 0; k < 8; ++k) {
      float v = (o[k] - mm[k]) * rsqrtf(vv[k] + 1e-5f) * gg[k] + bb[k];
      v = (v > 0.f) ? v : expm1f(v);
      ov[k] = (short)f2bf(v);
    }
    *(short8*)(hout + (size_t)n * FF + f0) = ov;
  }
}

// ---------------- launch ----------------
extern "C" void kernel_launch(void* const* d_in, const int* in_sizes, int n_in,
                              void* d_out, int out_size, void* d_ws, size_t ws_size,
                              hipStream_t stream) {
  const float* x   = (const float*)d_in[0];
  const int* ei    = (const int*)d_in[1];
  const float* W1  = (const float*)d_in[2];
  const float* as1 = (const float*)d_in[3];
  const float* ad1 = (const float*)d_in[4];
  const float* g1  = (const float*)d_in[5];
  const float* b1  = (const float*)d_in[6];
  const float* m1  = (const float*)d_in[7];
  const float* v1  = (const float*)d_in[8];
  const float* W2  = (const float*)d_in[9];
  const float* as2 = (const float*)d_in[10];
  const float* ad2 = (const float*)d_in[11];
  const float* g2  = (const float*)d_in[12];
  const float* b2  = (const float*)d_in[13];
  const float* m2  = (const float*)d_in[14];
  const float* v2  = (const float*)d_in[15];
  const float* Wc  = (const float*)d_in[16];
  const float* bc  = (const float*)d_in[17];

  const int N = in_sizes[0] / FF;
  const int E = in_sizes[1] / 2;
  const int* srcIdx = ei;
  const int* dstIdx = ei + E;

  char* ws = (char*)d_ws;
  size_t off = 0;
  auto take = [&](size_t bytes) -> void* {
    void* p = ws + off;
    off += (bytes + 255) & ~(size_t)255;
    return p;
  };
  int* deg        = (int*)take((size_t)N * 4);
  int* excl       = (int*)take((size_t)N * 4);
  int* csum       = (int*)take(256 * 4);
  int* row_start  = (int*)take(((size_t)N + 1) * 4);
  int* cursor     = (int*)take((size_t)N * 4);
  int* sorted_src = (int*)take((size_t)E * 4);
  float* alpha    = (float*)take((size_t)E * NHEAD * 4);
  float* sS       = (float*)take((size_t)N * NHEAD * 4);
  float* sD       = (float*)take((size_t)N * NHEAD * 4);
  unsigned short* hpre = (unsigned short*)take((size_t)N * FF * 2);
  unsigned short* hact = (unsigned short*)take((size_t)N * FF * 2);
  unsigned short* xb   = (unsigned short*)take((size_t)N * FF * 2);
  unsigned short* w1b  = (unsigned short*)take((size_t)FF * FF * 2);
  unsigned short* w2b  = (unsigned short*)take((size_t)FF * FF * 2);
  unsigned short* wcb  = (unsigned short*)take((size_t)64 * FF * 2);

  const int tpb = 256;

  // fused dtype conversions (1 dispatch)
  {
    int n0 = (N * FF) / 4, n1 = (FF * FF) / 4, n2 = (FF * FF) / 4, n3 = (64 * FF) / 4;
    int tot = n0 + n1 + n2 + n3;
    cvt4_kernel<<<(tot + tpb - 1) / tpb, tpb, 0, stream>>>(x, n0, W1, n1, W2, n2, Wc, n3,
                                                           xb, w1b, w2b, wcb);
  }

  // CSR build (dst-sorted edge list), reused by both layers
  hipMemsetAsync(deg, 0, (size_t)N * 4, stream);
  hist_kernel<<<(E + tpb - 1) / tpb, tpb, 0, stream>>>(dstIdx, deg, E, N);
  int nchunks = (N + 1023) / 1024;
  scan_chunks<<<nchunks, 256, 0, stream>>>(deg, excl, csum, N);
  scan_sums<<<1, 64, 0, stream>>>(csum, nchunks);
  finalize_rows<<<(N + tpb - 1) / tpb, tpb, 0, stream>>>(excl, csum, row_start, cursor, N, E);
  scatter_kernel<<<(E + tpb - 1) / tpb, tpb, 0, stream>>>(srcIdx, dstIdx, cursor, sorted_src, E, N);

  int nhBlocks = (N * NHEAD + tpb - 1) / tpb;
  int aggBlocks = (N + 3) / 4;
  int gemmBlocks = (N + 63) / 64;        // 64 rows/block, 256 cols
  int headBlocks = (N + 255) / 256;      // 256 rows/block, 64 cols

  // layer 1 (scores fused into GEMM epilogue)
  gemm_bt<4, true, true><<<gemmBlocks, 256, 0, stream>>>(
      xb, w1b, (float*)nullptr, hpre, (const float*)nullptr, as1, ad1, sS, sD, N);
  stats_alpha_kernel<<<nhBlocks, tpb, 0, stream>>>(sS, sD, row_start, sorted_src, alpha, N);
  aggregate_kernel<<<aggBlocks, 256, 0, stream>>>(hpre, alpha, row_start, sorted_src,
                                                  g1, b1, m1, v1, hact, N);
  // layer 2
  gemm_bt<4, true, true><<<gemmBlocks, 256, 0, stream>>>(
      hact, w2b, (float*)nullptr, hpre, (const float*)nullptr, as2, ad2, sS, sD, N);
  stats_alpha_kernel<<<nhBlocks, tpb, 0, stream>>>(sS, sD, row_start, sorted_src, alpha, N);
  aggregate_kernel<<<aggBlocks, 256, 0, stream>>>(hpre, alpha, row_start, sorted_src,
                                                  g2, b2, m2, v2, hact, N);
  // classifier head -> fp32 out (+bias)
  gemm_bt<1, false, false><<<headBlocks, 256, 0, stream>>>(
      hact, wcb, (float*)d_out, (unsigned short*)nullptr, bc,
      (const float*)nullptr, (const float*)nullptr, (float*)nullptr, (float*)nullptr, N);
}